// Round 18
// baseline (174.453 us; speedup 1.0000x reference)
//
#include <hip/hip_runtime.h>

// 3x3 SAME conv + bias + ReLU, N=32, Cin=Cout=256, H=W=56, fp32 in/out.
// v18 = v17 with 32x32x16 MFMA fragments + halo-zero instead of full memset:
//  - wave tile 64x64 as 2x2 of mfma_f32_32x32x16_bf16 (acc 2x2x16=64 regs):
//    LDS reads drop 24 -> 16 per wave-step (A 2x4 + B 2x4 b128), and the
//    32x32 pipe is ~15% faster than 16x16 (2495 vs 2176 TF ubench).
//  - read swizzle for 32x32 frags: chunk = (ks*2+hi) ^ (row&7), row==l&31
//    (beat-wise conflict-free vs the store-side involution, as v17).
//  - x_t PADDED [n][58x58][512B]; only the 3.7MB halo is zeroed (fused
//    into wcvt's grid) - no 55MB memset dispatch.
//  - BM=128co x BN=128px, 4 waves, BK=64, 36 steps, 2-phase dbuf,
//    1 barrier/step, 2 blocks/CU. Staging machinery byte-identical to v17.

#define GLOBAL_AS __attribute__((address_space(1)))
#define LDS_AS __attribute__((address_space(3)))

typedef __attribute__((ext_vector_type(8))) short short8;
typedef __attribute__((ext_vector_type(4))) float f32x4;
typedef __attribute__((ext_vector_type(16))) float f32x16;
typedef __attribute__((ext_vector_type(4))) unsigned int u32x4;

#define CIN   256
#define HWS   3136        // 56*56
#define PTOT  100352      // 32*3136
#define KTOT  2304        // CIN*9
#define IMGP  3364        // 58*58 padded granules per image
#define XTOFF 1310720     // x_t offset in ws
#define XTBYTES ((size_t)32 * IMGP * 512)
#define WSNEED (XTOFF + XTBYTES)

__device__ __forceinline__ unsigned short f2bf(float f) {
  unsigned u = __builtin_bit_cast(unsigned, f);
  return (unsigned short)((u + 0x7fffu + ((u >> 16) & 1u)) >> 16);  // RNE
}

// blocks < 2304: weights OIHW fp32 -> bf16 K-step-major wf[co][s*64+c].
// blocks >= 2304 (912 of them): zero the x_t halo (228 granules/image).
__global__ void wcvt_kernel(const float* __restrict__ w, unsigned char* __restrict__ ws) {
  const int bid = blockIdx.x;
  if (bid >= 2304) {
    const unsigned i = (unsigned)(bid - 2304) * 256 + threadIdx.x; // u32x4 slot
    if (i < 233472u) {                    // 32 img * 228 gran * 32 slots
      const int slot = i & 31;
      const int g    = i >> 5;
      const int img  = g / 228;
      const int hg   = g - img * 228;
      int r, c;
      if (hg < 58)        { r = 0;            c = hg; }
      else if (hg < 116)  { r = 57;           c = hg - 58; }
      else if (hg < 172)  { r = hg - 116 + 1; c = 0; }
      else                { r = hg - 172 + 1; c = 57; }
      const u32x4 z = {0u, 0u, 0u, 0u};
      *(u32x4*)(ws + XTOFF + ((size_t)img * IMGP + r * 58 + c) * 512 + slot * 16) = z;
    }
    return;
  }
  int o = bid * 256 + threadIdx.x;           // 0..589823
  int co = o / KTOT;
  int r  = o - co * KTOT;
  int s  = r >> 6;
  int c  = r & 63;
  int cq = s / 9;
  int tap = s - cq * 9;
  ((unsigned short*)ws)[o] = f2bf(w[co * KTOT + (cq * 64 + c) * 9 + tap]);
}

// x NCHW fp32 -> x_t padded [n][(h+1)*58+(w+1)][256ci] bf16 via LDS transpose.
__global__ __launch_bounds__(256) void xcvt_kernel(const float* __restrict__ x,
                                                   unsigned char* __restrict__ ws) {
  __shared__ float lt[64 * 257];
  const int pg0 = blockIdx.x * 64;       // 64-px tile, never crosses images
  const int n   = pg0 / HWS;
  const int pi0 = pg0 - n * HWS;
  const int t   = threadIdx.x;
  {
    const int px = t & 63;
    const int cg = t >> 6;               // 0..3 (wave-uniform)
    const float* xb = x + ((size_t)n * 256) * HWS + pi0 + px;
#pragma unroll 8
    for (int i = 0; i < 64; ++i) {
      const int c = i * 4 + cg;
      lt[px * 257 + c] = xb[(size_t)c * HWS];
    }
  }
  __syncthreads();
  {
    const int slot = t & 31;             // 16B slot = 8 channels (32 slots/row)
    const int pxw  = t >> 5;             // 0..7
    unsigned char* xt = ws + XTOFF;
#pragma unroll
    for (int i = 0; i < 8; ++i) {
      const int p  = i * 8 + pxw;
      const int pi = pi0 + p;
      const int h  = pi / 56;
      const int wcol = pi - h * 56;
      const size_t gran = (size_t)n * IMGP + (h + 1) * 58 + (wcol + 1);
      const float* r = &lt[p * 257 + slot * 8];
      u32x4 v;
#pragma unroll
      for (int j = 0; j < 4; ++j)
        v[j] = (unsigned)f2bf(r[2 * j]) | ((unsigned)f2bf(r[2 * j + 1]) << 16);
      *(u32x4*)(xt + gran * 512 + slot * 16) = v;
    }
  }
}

#define DTAP(tp) (((((tp) / 3) - 1) * 58 + ((tp) % 3) - 1) * 512)

__global__ __launch_bounds__(256, 2) void conv_kernel(
    const unsigned char* __restrict__ ws, const float* __restrict__ bias,
    float* __restrict__ out) {
  // LDS: buf{0,1} x (A 16KB + B 16KB)
  __shared__ __align__(16) unsigned char smem[65536];

  const unsigned char* wf = ws;
  const unsigned char* xt = ws + XTOFF;

  const int bid = blockIdx.x;
  const int sw  = (bid & 7) * 196 + (bid >> 3);  // XCD-chunked, bijective (1568=8*196)
  const int co0 = (sw & 1) * 128;
  const int p0  = (sw >> 1) * 128;               // global pixel base

  const int t    = threadIdx.x;
  const int lane = t & 63;
  const int wave = t >> 6;     // 0..3
  const int wm   = wave & 1;   // co 64-half
  const int wn   = wave >> 1;  // px 64-half
  const int l31  = lane & 31;
  const int hi   = lane >> 5;  // 0/1
  const int l7   = lane & 7;
  const int l8   = lane >> 3;

  // staging: pre-swizzled chunk offset within a 128B row (v17 involution)
  const unsigned chanoff = (unsigned)((l7 * 16) ^ ((l8 & 7) << 4));

  // ---- staging pointers (mutable, advanced once per 18-step body) ----
  const unsigned char* aP[4];
  const unsigned char* bP[4];
#pragma unroll
  for (int i = 0; i < 4; ++i) {
    const int row = wave * 32 + i * 8 + l8;       // 0..127
    aP[i] = wf + (size_t)(co0 + row) * 4608 + chanoff;
    const int pg = p0 + row;
    const int n  = pg / HWS;
    const int pi = pg - n * HWS;
    const int h  = pi / 56;
    const int wc = pi - h * 56;
    bP[i] = xt + ((size_t)n * IMGP + (h + 1) * 58 + (wc + 1)) * 512 + chanoff;
  }
  const unsigned ldsA = (unsigned)(wave * 4096);  // + i*1024 per op

  // ---- compute-phase per-lane base addresses (32x32 frags) ----
  // logical chunk for k-slice ks: c = ks*2 + hi; physical = c ^ (row&7),
  // row = l31 (+32*mi / +64*wm, multiples of 8 don't affect row&7).
  const unsigned char* pA[4];
  const unsigned char* pB[4];
#pragma unroll
  for (int ks = 0; ks < 4; ++ks) {
    const unsigned krd = (unsigned)(((ks * 2 + hi) ^ l7) * 16);
    pA[ks] = smem + wm * 8192 + l31 * 128 + krd;
    pB[ks] = smem + 16384 + wn * 8192 + l31 * 128 + krd;
  }

  f32x16 acc[2][2];
#pragma unroll
  for (int mi = 0; mi < 2; ++mi)
#pragma unroll
    for (int ni = 0; ni < 2; ++ni)
#pragma unroll
      for (int j = 0; j < 16; ++j) acc[mi][ni][j] = 0.f;

#define STAGE(DB, AOFF, BD)                                                   \
  {                                                                           \
    _Pragma("unroll") for (int i_ = 0; i_ < 4; ++i_)                          \
        __builtin_amdgcn_global_load_lds(                                     \
            (const GLOBAL_AS unsigned int*)(aP[i_] + (AOFF)),                 \
            (LDS_AS unsigned int*)(smem + (DB)*32768 + ldsA + i_ * 1024),     \
            16, 0, 0);                                                        \
    _Pragma("unroll") for (int i_ = 0; i_ < 4; ++i_)                          \
        __builtin_amdgcn_global_load_lds(                                     \
            (const GLOBAL_AS unsigned int*)(bP[i_] + (BD)),                   \
            (LDS_AS unsigned int*)(smem + (DB)*32768 + 16384 + ldsA +         \
                                   i_ * 1024),                                \
            16, 0, 0);                                                        \
  }

#define COMP(BUF)                                                             \
  {                                                                           \
    _Pragma("unroll") for (int ks = 0; ks < 4; ++ks) {                        \
      short8 av[2], bv[2];                                                    \
      _Pragma("unroll") for (int mi = 0; mi < 2; ++mi)                        \
          av[mi] = *(const short8*)(pA[ks] + (BUF)*32768 + mi * 4096);        \
      _Pragma("unroll") for (int ni = 0; ni < 2; ++ni)                        \
          bv[ni] = *(const short8*)(pB[ks] + (BUF)*32768 + ni * 4096);        \
      _Pragma("unroll") for (int mi = 0; mi < 2; ++mi)                        \
        _Pragma("unroll") for (int ni = 0; ni < 2; ++ni)                      \
            acc[mi][ni] = __builtin_amdgcn_mfma_f32_32x32x16_bf16(            \
                av[mi], bv[ni], acc[mi][ni], 0, 0, 0);                        \
    }                                                                         \
  }

// step J (0..16) of an 18-step body: stage s=J+1, compute s=J, sync
#define STEPJ(J)                                                              \
  STAGE(((J) + 1) & 1, ((J) + 1) * 128,                                       \
        DTAP((((J) + 1) % 9)) + (((J) + 1) / 9) * 128);                       \
  COMP((J)&1);                                                                \
  __syncthreads();

  // ---- prologue: stage s=0 into buf0 ----
  STAGE(0, 0, DTAP(0))
  __syncthreads();

#pragma unroll 1
  for (int gg = 0; gg < 2; ++gg) {
    STEPJ(0) STEPJ(1) STEPJ(2) STEPJ(3) STEPJ(4) STEPJ(5) STEPJ(6) STEPJ(7)
    STEPJ(8) STEPJ(9) STEPJ(10) STEPJ(11) STEPJ(12) STEPJ(13) STEPJ(14)
    STEPJ(15) STEPJ(16)
    // step 17: stage next body's s=0 (after pointer advance), compute, sync
    if (gg == 0) {
#pragma unroll
      for (int i = 0; i < 4; ++i) {
        aP[i] += 2304;   // 18 steps * 128B
        bP[i] += 256;    // 2 channel-chunks * 128B
      }
      STAGE(0, 0, DTAP(0))
    }
    COMP(1)
    __syncthreads();
  }
#undef STEPJ
#undef COMP
#undef STAGE

  // ---- epilogue: bias + ReLU.
  // 32x32 C/D: col = lane&31, row = (j&3) + 8*(j>>2) + 4*hi (m74/m101) ----
#pragma unroll
  for (int mi = 0; mi < 2; ++mi) {
#pragma unroll
    for (int ni = 0; ni < 2; ++ni) {
      const int pgb = p0 + wn * 64 + ni * 32;   // 32-span within one image
      const int n   = pgb / HWS;
      const int pib = pgb - n * HWS;
#pragma unroll
      for (int j = 0; j < 16; ++j) {
        const int row = co0 + wm * 64 + mi * 32 + (j & 3) + 8 * (j >> 2) + 4 * hi;
        float v = acc[mi][ni][j] + bias[row];
        out[(size_t)(n * 256 + row) * HWS + pib + l31] = fmaxf(v, 0.f);
      }
    }
  }
}

// Correct-but-slow fallback if workspace is too small (not expected).
__global__ void naive_kernel(const float* __restrict__ x, const float* __restrict__ w,
                             const float* __restrict__ bias, float* __restrict__ out) {
  int idx = blockIdx.x * 256 + threadIdx.x;
  if (idx >= 32 * 256 * HWS) return;
  int n  = idx / (256 * HWS);
  int r  = idx - n * 256 * HWS;
  int co = r / HWS;
  int p  = r - co * HWS;
  int h = p / 56, ww = p - h * 56;
  float s = bias[co];
  const float* xb = x + (size_t)n * 256 * HWS;
  const float* wbp = w + (size_t)co * KTOT;
  for (int ci = 0; ci < 256; ++ci) {
    const float* xc = xb + (size_t)ci * HWS;
    const float* wc = wbp + ci * 9;
    for (int kh = 0; kh < 3; ++kh) {
      int hh = h + kh - 1;
      if ((unsigned)hh >= 56u) continue;
      for (int kw = 0; kw < 3; ++kw) {
        int w2 = ww + kw - 1;
        if ((unsigned)w2 >= 56u) continue;
        s += xc[hh * 56 + w2] * wc[kh * 3 + kw];
      }
    }
  }
  out[idx] = fmaxf(s, 0.f);
}

extern "C" void kernel_launch(void* const* d_in, const int* in_sizes, int n_in,
                              void* d_out, int out_size, void* d_ws, size_t ws_size,
                              hipStream_t stream) {
  const float* x    = (const float*)d_in[0];
  const float* w    = (const float*)d_in[1];
  const float* bias = (const float*)d_in[2];
  float* out        = (float*)d_out;

  if (ws_size < WSNEED) {
    hipLaunchKernelGGL(naive_kernel, dim3((32 * 256 * HWS + 255) / 256), dim3(256),
                       0, stream, x, w, bias, out);
    return;
  }
  unsigned char* ws = (unsigned char*)d_ws;
  hipLaunchKernelGGL(wcvt_kernel, dim3(3216), dim3(256), 0, stream, w, ws);
  hipLaunchKernelGGL(xcvt_kernel, dim3(PTOT / 64), dim3(256), 0, stream, x, ws);
  hipLaunchKernelGGL(conv_kernel, dim3(1568), dim3(256), 0, stream, ws, bias, out);
}